// Round 15
// baseline (745.633 us; speedup 1.0000x reference)
//
#include <hip/hip_runtime.h>

#define N_NODES 100000
#define N_EDGES 1600000
#define N_GRAPHS 1024
#define HID 128
#define LAYERS 4
#define LN_EPS 1e-5f
#define NB_SCAN 391  // ceil(100000/256)
#define GTS 136      // ushort row stride for bf16 LDS planes (16B-aligned)
#define NB_PROJ 50000
#define NB_WCONV 512
#define NB_EDGE4 1563  // ceil(N_EDGES/4/256)

typedef __attribute__((ext_vector_type(8))) short bf16x8;
typedef __attribute__((ext_vector_type(4))) float f32x4;

__device__ __forceinline__ unsigned short f2bf(float x) {
    unsigned v = __float_as_uint(x);
    return (unsigned short)((v + 0x7fffu + ((v >> 16) & 1u)) >> 16);
}
__device__ __forceinline__ float bfval(unsigned short u) {
    return __uint_as_float((unsigned)u << 16);
}

// ------- prep: input projection + MFMA weight pre-swizzle ------------
__global__ __launch_bounds__(256) void k_prep(
    const float* __restrict__ x, const float* __restrict__ inW,
    const float* __restrict__ inb, float* __restrict__ h,
    unsigned short* __restrict__ hb,
    const float* __restrict__ w1, const float* __restrict__ w2,
    unsigned short* __restrict__ wf_hi, unsigned short* __restrict__ wf_lo) {
    if (blockIdx.x < NB_PROJ) {
        int idx = blockIdx.x * 256 + threadIdx.x;  // N_NODES*HID exact
        int n = idx >> 7, c = idx & 127;
        const float* xr = x + n * 7;
        float s = inb[c];
#pragma unroll
        for (int k = 0; k < 7; ++k) s += xr[k] * inW[k * HID + c];
        h[idx] = s;
        hb[idx] = f2bf(s);
    } else {
        int idx = (blockIdx.x - NB_PROJ) * 256 + threadIdx.x;  // LAYERS*2*16384
        int wid = idx >> 14;
        int layer = wid >> 1, which = wid & 1;
        int within = idx & 16383;
        int nt = within >> 11;
        int ks = (within >> 9) & 3;
        int ln = (within >> 3) & 63;
        int j = within & 7;
        const float* W = (which ? w2 : w1) + layer * HID * HID;
        int k = ks * 32 + (ln >> 4) * 8 + j;
        int n = nt * 16 + (ln & 15);
        float v = W[k * HID + n];
        unsigned short hi = f2bf(v);
        wf_hi[idx] = hi;
        wf_lo[idx] = f2bf(v - bfval(hi));
    }
}

// ---------------- CSR build: histogram of dst, 4 edges/thread --------
// 100k counters, ~16-way avg contention: fine. (R10 lesson: do NOT
// atomically build the 391-entry block-sum array -- 4100-way contention
// serialized it. R14 lesson: 1 atomic/thread is latency-bound; 4
// independent atomics per thread overlap their latencies.)
__global__ __launch_bounds__(256) void k_hist(
    const int* __restrict__ ei, int* __restrict__ deg) {
    const int e0 = (blockIdx.x * 256 + threadIdx.x) * 4;
    if (e0 + 4 <= N_EDGES) {
        const int4 d = *(const int4*)(ei + N_EDGES + e0);
        atomicAdd(&deg[d.x], 1);
        atomicAdd(&deg[d.y], 1);
        atomicAdd(&deg[d.z], 1);
        atomicAdd(&deg[d.w], 1);
    }
    // N_EDGES % 4 == 0 and grid covers it exactly: no tail needed
}

// ---------------- CSR build: parallel 3-stage scan -------------------
__global__ __launch_bounds__(256) void k_scan1(
    const int* __restrict__ deg, int* __restrict__ bsum) {
    const int i = blockIdx.x * 256 + threadIdx.x;
    int v = (i < N_NODES) ? deg[i] : 0;
#pragma unroll
    for (int off = 1; off < 64; off <<= 1) v += __shfl_xor(v, off);
    __shared__ int wsum[4];
    if ((threadIdx.x & 63) == 0) wsum[threadIdx.x >> 6] = v;
    __syncthreads();
    if (threadIdx.x == 0) bsum[blockIdx.x] = wsum[0] + wsum[1] + wsum[2] + wsum[3];
}

__global__ __launch_bounds__(512) void k_scan2(
    const int* __restrict__ bsum, int* __restrict__ bpre) {
    __shared__ int tmp[512];
    const int t = threadIdx.x;
    int v = (t < NB_SCAN) ? bsum[t] : 0;
    tmp[t] = v;
    __syncthreads();
    for (int off = 1; off < 512; off <<= 1) {
        int u = (t >= off) ? tmp[t - off] : 0;
        __syncthreads();
        tmp[t] += u;
        __syncthreads();
    }
    if (t < NB_SCAN) bpre[t] = tmp[t] - v;  // exclusive
}

__global__ __launch_bounds__(256) void k_scan3(
    const int* __restrict__ deg, const int* __restrict__ bpre,
    int* __restrict__ row_ptr, int* __restrict__ cursor) {
    __shared__ int tmp[256];
    const int t = threadIdx.x;
    const int i = blockIdx.x * 256 + t;
    int d = (i < N_NODES) ? deg[i] : 0;
    tmp[t] = d;
    __syncthreads();
    for (int off = 1; off < 256; off <<= 1) {
        int u = (t >= off) ? tmp[t - off] : 0;
        __syncthreads();
        tmp[t] += u;
        __syncthreads();
    }
    if (i < N_NODES) {
        const int ex = bpre[blockIdx.x] + tmp[t] - d;
        row_ptr[i] = ex;
        cursor[i] = ex;
        if (i == N_NODES - 1) row_ptr[N_NODES] = N_EDGES;
    }
}

// ------- CSR build: scatter edges into sorted slots, 4 edges/thread --
// 4 independent atomic+store chains in flight per thread (R14: single
// chain was latency-bound at 118 us, VALUBusy 0.4%).
__global__ __launch_bounds__(256) void k_scatter(
    const int* __restrict__ ei, const float* __restrict__ ea,
    int* __restrict__ cursor, float4* __restrict__ edata) {
    const int e0 = (blockIdx.x * 256 + threadIdx.x) * 4;
    if (e0 + 4 <= N_EDGES) {
        const int4 src = *(const int4*)(ei + e0);
        const int4 dst = *(const int4*)(ei + N_EDGES + e0);
        const float4 q0 = *(const float4*)(ea + (size_t)e0 * 3);
        const float4 q1 = *(const float4*)(ea + (size_t)e0 * 3 + 4);
        const float4 q2 = *(const float4*)(ea + (size_t)e0 * 3 + 8);
        const int p0 = atomicAdd(&cursor[dst.x], 1);
        const int p1 = atomicAdd(&cursor[dst.y], 1);
        const int p2 = atomicAdd(&cursor[dst.z], 1);
        const int p3 = atomicAdd(&cursor[dst.w], 1);
        edata[p0] = make_float4(q0.x, q0.y, q0.z, __int_as_float(src.x));
        edata[p1] = make_float4(q0.w, q1.x, q1.y, __int_as_float(src.y));
        edata[p2] = make_float4(q1.z, q1.w, q2.x, __int_as_float(src.z));
        edata[p3] = make_float4(q2.y, q2.z, q2.w, __int_as_float(src.w));
    }
}

// -- phase-1 edge macros (macros only: outlined helpers spill, R4/R5) --
// Edge tile in registers (cur = edata[t+lane]); attrs/src via v_readlane.
// Row selection: RUNNING accumulator + scalar boundary flush (edges are
// CSR-sorted, so boundaries occur only ~3x per wave stream).
// Flush of row r sets the next boundary to rp(r+2).
#define FLUSHSTEP {                                                            \
    if (rcur == 0)      { a0x = ax; a0y = ay; rnext = rp2; }                   \
    else if (rcur == 1) { a1x = ax; a1y = ay; rnext = rp3; }                   \
    else                { a2x = ax; a2y = ay; rnext = 0x7fffffff; }            \
    ax = 0.f; ay = 0.f; ++rcur; }

#define EL(JJ)                                                                 \
    const int s##JJ = __builtin_amdgcn_readlane(__float_as_int(cur.w), j + JJ); \
    const unsigned gq##JJ = *(const unsigned*)(hbin + (long)s##JJ * HID + c2);

#define EC(JJ) {                                                               \
    const int gi = t + j + (JJ);                                               \
    while (gi >= rnext) FLUSHSTEP                                              \
    const float ax_ = __uint_as_float(__builtin_amdgcn_readlane(__float_as_int(cur.x), j + JJ)); \
    const float ay_ = __uint_as_float(__builtin_amdgcn_readlane(__float_as_int(cur.y), j + JJ)); \
    const float az_ = __uint_as_float(__builtin_amdgcn_readlane(__float_as_int(cur.z), j + JJ)); \
    const float gx = __uint_as_float(gq##JJ << 16) + ebv.x;                    \
    const float gy = __uint_as_float(gq##JJ & 0xffff0000u) + ebv.y;            \
    const float mx = fmaxf(fmaf(az_, ew2.x, fmaf(ay_, ew1.x, fmaf(ax_, ew0.x, gx))), 0.f); \
    const float my = fmaxf(fmaf(az_, ew2.y, fmaf(ay_, ew1.y, fmaf(ax_, ew0.y, gy))), 0.f); \
    ax += mx; ay += my; }

#define ROW_OUT(R, AX, AY) {                                                   \
    const float2 hv = *(const float2*)(h + (long)(nb + (R)) * HID + c2);       \
    const float gx = hv.x + (AX), gy = hv.y + (AY);                            \
    const unsigned short hx = f2bf(gx), hy = f2bf(gy);                         \
    const unsigned short lx = f2bf(gx - bfval(hx)), ly = f2bf(gy - bfval(hy)); \
    *(unsigned*)&gt_hi[(r0 + (R)) * GTS + c2] = (unsigned)hx | ((unsigned)hy << 16); \
    *(unsigned*)&gt_lo[(r0 + (R)) * GTS + c2] = (unsigned)lx | ((unsigned)ly << 16); }

#define T1_OUT(CC, NT) {                                                       \
    const float4 bv = *(const float4*)(b1 + (NT) * 16 + q4);                   \
    const float v0 = fmaxf(CC[0] + bv.x, 0.f);                                 \
    const float v1 = fmaxf(CC[1] + bv.y, 0.f);                                 \
    const float v2 = fmaxf(CC[2] + bv.z, 0.f);                                 \
    const float v3 = fmaxf(CC[3] + bv.w, 0.f);                                 \
    const unsigned short h0_ = f2bf(v0), h1_ = f2bf(v1), h2_ = f2bf(v2), h3_ = f2bf(v3); \
    const unsigned short l0_ = f2bf(v0 - bfval(h0_)), l1_ = f2bf(v1 - bfval(h1_)); \
    const unsigned short l2_ = f2bf(v2 - bfval(h2_)), l3_ = f2bf(v3 - bfval(h3_)); \
    *(uint2*)&t1_hi[ln15 * GTS + (NT) * 16 + q4] =                             \
        make_uint2((unsigned)h0_ | ((unsigned)h1_ << 16), (unsigned)h2_ | ((unsigned)h3_ << 16)); \
    *(uint2*)&t1_lo[ln15 * GTS + (NT) * 16 + q4] =                             \
        make_uint2((unsigned)l0_ | ((unsigned)l1_ << 16), (unsigned)l2_ | ((unsigned)l3_ << 16)); }

// ------- fused gather-aggregate + MFMA MLP + residual + layernorm ----
__global__ __launch_bounds__(256, 8) void k_node_update(
    const float4* __restrict__ edata, const int* __restrict__ row_ptr,
    const float* __restrict__ eW, const float* __restrict__ eb,
    float* __restrict__ h, const unsigned short* __restrict__ hbin,
    unsigned short* __restrict__ hbout,
    const unsigned short* __restrict__ w1f_hi, const unsigned short* __restrict__ w1f_lo,
    const unsigned short* __restrict__ w2f_hi, const unsigned short* __restrict__ w2f_lo,
    const float* __restrict__ b1, const float* __restrict__ b2,
    const float* __restrict__ gamma, const float* __restrict__ beta) {
    __shared__ __align__(16) unsigned char smem[17408];
    float* stats = (float*)smem;                              // [4][32] f32, phase 3 (aliases gt_hi)
    unsigned short* gt_hi = (unsigned short*)(smem + 0);      // [16][GTS]
    unsigned short* gt_lo = (unsigned short*)(smem + 4352);
    unsigned short* t1_hi = (unsigned short*)(smem + 8704);
    unsigned short* t1_lo = (unsigned short*)(smem + 13056);

    const int wave = threadIdx.x >> 6;
    const int lane = threadIdx.x & 63;
    const int n0 = blockIdx.x * 16;
    const int r0 = wave * 4;
    const int c2 = lane * 2;

    // ---- phase 1: gather-aggregate, full wave per edge, zero LDS ----
    {
        const float2 ew0 = *(const float2*)(eW + 0 * HID + c2);
        const float2 ew1 = *(const float2*)(eW + 1 * HID + c2);
        const float2 ew2 = *(const float2*)(eW + 2 * HID + c2);
        const float2 ebv = *(const float2*)(eb + c2);
        const int nb = n0 + r0;
        const int rp0 = __builtin_amdgcn_readfirstlane(row_ptr[nb + 0]);
        const int rp1 = __builtin_amdgcn_readfirstlane(row_ptr[nb + 1]);
        const int rp2 = __builtin_amdgcn_readfirstlane(row_ptr[nb + 2]);
        const int rp3 = __builtin_amdgcn_readfirstlane(row_ptr[nb + 3]);
        const int rp4 = __builtin_amdgcn_readfirstlane(row_ptr[nb + 4]);

        float a0x = 0.f, a0y = 0.f, a1x = 0.f, a1y = 0.f;
        float a2x = 0.f, a2y = 0.f, a3x = 0.f, a3y = 0.f;
        float ax = 0.f, ay = 0.f;   // running accumulator (current row)
        int rcur = 0;               // current row index (scalar)
        int rnext = rp1;            // next row boundary

        float4 cur, nxt;
        if (rp0 + lane < rp4) cur = edata[rp0 + lane];
        for (int t = rp0; t < rp4; t += 64) {
            const int cnt = (rp4 - t < 64) ? (rp4 - t) : 64;
            if (t + 64 + lane < rp4) nxt = edata[t + 64 + lane];  // prefetch
            int j = 0;
            for (; j + 16 <= cnt; j += 16) {
                EL(0) EL(1) EL(2) EL(3) EL(4) EL(5) EL(6) EL(7)
                EL(8) EL(9) EL(10) EL(11) EL(12) EL(13) EL(14) EL(15)
                EC(0) EC(1) EC(2) EC(3) EC(4) EC(5) EC(6) EC(7)
                EC(8) EC(9) EC(10) EC(11) EC(12) EC(13) EC(14) EC(15)
            }
            for (; j + 4 <= cnt; j += 4) {
                EL(0) EL(1) EL(2) EL(3)
                EC(0) EC(1) EC(2) EC(3)
            }
            for (; j < cnt; ++j) {
                EL(0)
                EC(0)
            }
            cur = nxt;
        }
        // tail: running acc belongs to row rcur; rows after it stay zero
        if (rcur == 0)      { a0x = ax; a0y = ay; }
        else if (rcur == 1) { a1x = ax; a1y = ay; }
        else if (rcur == 2) { a2x = ax; a2y = ay; }
        else                { a3x = ax; a3y = ay; }
        ROW_OUT(0, a0x, a0y)
        ROW_OUT(1, a1x, a1y)
        ROW_OUT(2, a2x, a2y)
        ROW_OUT(3, a3x, a3y)
    }
    __syncthreads();

    const int ln15 = lane & 15;
    const int q8 = (lane >> 4) * 8;
    const int q4 = (lane >> 4) * 4;
    const int nt0 = wave * 2, nt1 = nt0 + 1;

    // ---- phase 2: t1 = relu(gt @ w1 + b1) via MFMA (D[hid][node]) ----
    {
        f32x4 c0 = {0.f, 0.f, 0.f, 0.f};
        f32x4 c1 = {0.f, 0.f, 0.f, 0.f};
#pragma unroll
        for (int ks = 0; ks < 4; ++ks) {
            const bf16x8 bh = *(const bf16x8*)&gt_hi[ln15 * GTS + ks * 32 + q8];
            const bf16x8 bl = *(const bf16x8*)&gt_lo[ln15 * GTS + ks * 32 + q8];
            const bf16x8 a0h = *(const bf16x8*)(w1f_hi + (((nt0 * 4 + ks) * 64 + lane) << 3));
            const bf16x8 a0l = *(const bf16x8*)(w1f_lo + (((nt0 * 4 + ks) * 64 + lane) << 3));
            const bf16x8 a1h = *(const bf16x8*)(w1f_hi + (((nt1 * 4 + ks) * 64 + lane) << 3));
            const bf16x8 a1l = *(const bf16x8*)(w1f_lo + (((nt1 * 4 + ks) * 64 + lane) << 3));
            c0 = __builtin_amdgcn_mfma_f32_16x16x32_bf16(a0h, bh, c0, 0, 0, 0);
            c0 = __builtin_amdgcn_mfma_f32_16x16x32_bf16(a0h, bl, c0, 0, 0, 0);
            c0 = __builtin_amdgcn_mfma_f32_16x16x32_bf16(a0l, bh, c0, 0, 0, 0);
            c1 = __builtin_amdgcn_mfma_f32_16x16x32_bf16(a1h, bh, c1, 0, 0, 0);
            c1 = __builtin_amdgcn_mfma_f32_16x16x32_bf16(a1h, bl, c1, 0, 0, 0);
            c1 = __builtin_amdgcn_mfma_f32_16x16x32_bf16(a1l, bh, c1, 0, 0, 0);
        }
        T1_OUT(c0, nt0)
        T1_OUT(c1, nt1)
    }
    __syncthreads();

    // ---- phase 3: u = h + relu(t1 @ w2 + b2) in regs; fused LN ----
    {
        f32x4 c0 = {0.f, 0.f, 0.f, 0.f};
        f32x4 c1 = {0.f, 0.f, 0.f, 0.f};
#pragma unroll
        for (int ks = 0; ks < 4; ++ks) {
            const bf16x8 bh = *(const bf16x8*)&t1_hi[ln15 * GTS + ks * 32 + q8];
            const bf16x8 bl = *(const bf16x8*)&t1_lo[ln15 * GTS + ks * 32 + q8];
            const bf16x8 a0h = *(const bf16x8*)(w2f_hi + (((nt0 * 4 + ks) * 64 + lane) << 3));
            const bf16x8 a0l = *(const bf16x8*)(w2f_lo + (((nt0 * 4 + ks) * 64 + lane) << 3));
            const bf16x8 a1h = *(const bf16x8*)(w2f_hi + (((nt1 * 4 + ks) * 64 + lane) << 3));
            const bf16x8 a1l = *(const bf16x8*)(w2f_lo + (((nt1 * 4 + ks) * 64 + lane) << 3));
            c0 = __builtin_amdgcn_mfma_f32_16x16x32_bf16(a0h, bh, c0, 0, 0, 0);
            c0 = __builtin_amdgcn_mfma_f32_16x16x32_bf16(a0h, bl, c0, 0, 0, 0);
            c0 = __builtin_amdgcn_mfma_f32_16x16x32_bf16(a0l, bh, c0, 0, 0, 0);
            c1 = __builtin_amdgcn_mfma_f32_16x16x32_bf16(a1h, bh, c1, 0, 0, 0);
            c1 = __builtin_amdgcn_mfma_f32_16x16x32_bf16(a1h, bl, c1, 0, 0, 0);
            c1 = __builtin_amdgcn_mfma_f32_16x16x32_bf16(a1l, bh, c1, 0, 0, 0);
        }
        const int row = n0 + ln15;
        const float4 b20 = *(const float4*)(b2 + nt0 * 16 + q4);
        const float4 b21 = *(const float4*)(b2 + nt1 * 16 + q4);
        const float4 hv0 = *(const float4*)(h + (long)row * HID + nt0 * 16 + q4);
        const float4 hv1 = *(const float4*)(h + (long)row * HID + nt1 * 16 + q4);
        float4 u0, u1;
        u0.x = hv0.x + fmaxf(c0[0] + b20.x, 0.f);
        u0.y = hv0.y + fmaxf(c0[1] + b20.y, 0.f);
        u0.z = hv0.z + fmaxf(c0[2] + b20.z, 0.f);
        u0.w = hv0.w + fmaxf(c0[3] + b20.w, 0.f);
        u1.x = hv1.x + fmaxf(c1[0] + b21.x, 0.f);
        u1.y = hv1.y + fmaxf(c1[1] + b21.y, 0.f);
        u1.z = hv1.z + fmaxf(c1[2] + b21.z, 0.f);
        u1.w = hv1.w + fmaxf(c1[3] + b21.w, 0.f);
        float s = u0.x + u0.y + u0.z + u0.w + u1.x + u1.y + u1.z + u1.w;
        float s2 = u0.x * u0.x + u0.y * u0.y + u0.z * u0.z + u0.w * u0.w +
                   u1.x * u1.x + u1.y * u1.y + u1.z * u1.z + u1.w * u1.w;
        s += __shfl_xor(s, 16); s2 += __shfl_xor(s2, 16);
        s += __shfl_xor(s, 32); s2 += __shfl_xor(s2, 32);
        if (lane < 16) {
            stats[wave * 32 + lane * 2 + 0] = s;
            stats[wave * 32 + lane * 2 + 1] = s2;
        }
        __syncthreads();
        const float S  = stats[0 * 32 + ln15 * 2] + stats[1 * 32 + ln15 * 2] +
                         stats[2 * 32 + ln15 * 2] + stats[3 * 32 + ln15 * 2];
        const float S2 = stats[0 * 32 + ln15 * 2 + 1] + stats[1 * 32 + ln15 * 2 + 1] +
                         stats[2 * 32 + ln15 * 2 + 1] + stats[3 * 32 + ln15 * 2 + 1];
        const float mu = S * (1.f / HID);
        const float var = S2 * (1.f / HID) - mu * mu;
        const float inv = rsqrtf(var + LN_EPS);
        const float4 gm0 = *(const float4*)(gamma + nt0 * 16 + q4);
        const float4 gm1 = *(const float4*)(gamma + nt1 * 16 + q4);
        const float4 bt0 = *(const float4*)(beta + nt0 * 16 + q4);
        const float4 bt1 = *(const float4*)(beta + nt1 * 16 + q4);
        float4 o0, o1;
        o0.x = (u0.x - mu) * inv * gm0.x + bt0.x;
        o0.y = (u0.y - mu) * inv * gm0.y + bt0.y;
        o0.z = (u0.z - mu) * inv * gm0.z + bt0.z;
        o0.w = (u0.w - mu) * inv * gm0.w + bt0.w;
        o1.x = (u1.x - mu) * inv * gm1.x + bt1.x;
        o1.y = (u1.y - mu) * inv * gm1.y + bt1.y;
        o1.z = (u1.z - mu) * inv * gm1.z + bt1.z;
        o1.w = (u1.w - mu) * inv * gm1.w + bt1.w;
        *(float4*)(h + (long)row * HID + nt0 * 16 + q4) = o0;
        *(float4*)(h + (long)row * HID + nt1 * 16 + q4) = o1;
        *(uint2*)(hbout + (long)row * HID + nt0 * 16 + q4) =
            make_uint2((unsigned)f2bf(o0.x) | ((unsigned)f2bf(o0.y) << 16),
                       (unsigned)f2bf(o0.z) | ((unsigned)f2bf(o0.w) << 16));
        *(uint2*)(hbout + (long)row * HID + nt1 * 16 + q4) =
            make_uint2((unsigned)f2bf(o1.x) | ((unsigned)f2bf(o1.y) << 16),
                       (unsigned)f2bf(o1.z) | ((unsigned)f2bf(o1.w) << 16));
    }
}

// -------- global mean pool: segmented reduction (batch is sorted) ----
__global__ __launch_bounds__(128) void k_pool(
    const float* __restrict__ h, const int* __restrict__ batch,
    float* __restrict__ sums, float* __restrict__ cnt) {
    const int c = threadIdx.x;
    const int n0 = blockIdx.x * 64;
    if (n0 >= N_NODES) return;
    const int nend = min(n0 + 64, N_NODES);
    int cur = batch[n0];
    float acc = 0.f;
    int runlen = 0;
    for (int n = n0; n < nend; ++n) {
        const int b = batch[n];
        if (b != cur) {
            atomicAdd(&sums[(long)cur * HID + c], acc);
            if (c == 0) atomicAdd(&cnt[cur], (float)runlen);
            acc = 0.f;
            runlen = 0;
            cur = b;
        }
        acc += h[(long)n * HID + c];
        ++runlen;
    }
    atomicAdd(&sums[(long)cur * HID + c], acc);
    if (c == 0) atomicAdd(&cnt[cur], (float)runlen);
}

// ---------------- head: 1 block per graph ----------------------------
__global__ __launch_bounds__(128) void k_head(
    const float* __restrict__ sums, const float* __restrict__ cnt,
    const float* __restrict__ fcW1, const float* __restrict__ fcb1,
    const float* __restrict__ fcW2, const float* __restrict__ fcb2,
    const float* __restrict__ fcW3, const float* __restrict__ fcb3,
    float* __restrict__ out) {
    __shared__ float p[HID];
    __shared__ float o1[HID];
    __shared__ float o2[64];
    const int g = blockIdx.x, t = threadIdx.x;
    const float c = fmaxf(cnt[g], 1.0f);
    p[t] = sums[g * HID + t] / c;
    __syncthreads();
    float s = fcb1[t];
    for (int k = 0; k < HID; ++k) s += p[k] * fcW1[k * HID + t];
    o1[t] = fmaxf(s, 0.f);
    __syncthreads();
    if (t < 64) {
        float s2 = fcb2[t];
        for (int k = 0; k < HID; ++k) s2 += o1[k] * fcW2[k * 64 + t];
        o2[t] = fmaxf(s2, 0.f);
    }
    __syncthreads();
    if (t < 64) {
        float v = o2[t] * fcW3[t];
#pragma unroll
        for (int off = 32; off > 0; off >>= 1) v += __shfl_down(v, off);
        if (t == 0) out[g] = v + fcb3[0];
    }
}

extern "C" void kernel_launch(void* const* d_in, const int* in_sizes, int n_in,
                              void* d_out, int out_size, void* d_ws, size_t ws_size,
                              hipStream_t stream) {
    const float* x    = (const float*)d_in[0];
    const int*   ei   = (const int*)d_in[1];
    const float* ea   = (const float*)d_in[2];
    const int*   batch= (const int*)d_in[3];
    const float* inW  = (const float*)d_in[4];
    const float* inb  = (const float*)d_in[5];
    const float* edgeW= (const float*)d_in[6];
    const float* edgeb= (const float*)d_in[7];
    const float* w1   = (const float*)d_in[8];
    const float* b1   = (const float*)d_in[9];
    const float* w2   = (const float*)d_in[10];
    const float* b2   = (const float*)d_in[11];
    const float* gamma= (const float*)d_in[12];
    const float* beta = (const float*)d_in[13];
    const float* fcW1 = (const float*)d_in[14];
    const float* fcb1 = (const float*)d_in[15];
    const float* fcW2 = (const float*)d_in[16];
    const float* fcb2 = (const float*)d_in[17];
    const float* fcW3 = (const float*)d_in[18];
    const float* fcb3 = (const float*)d_in[19];
    float* out = (float*)d_out;

    // workspace layout (16B-aligned blocks first): ~129 MB
    float4* edata = (float4*)d_ws;                                     // 25.6 MB
    float*  h     = (float*)(edata + N_EDGES);                         // 51.2 MB
    unsigned short* hb0 = (unsigned short*)(h + (size_t)N_NODES * HID);// 25.6 MB
    unsigned short* hb1 = hb0 + (size_t)N_NODES * HID;                 // 25.6 MB
    unsigned short* wf_hi = hb1 + (size_t)N_NODES * HID;               // 256 KB
    unsigned short* wf_lo = wf_hi + LAYERS * 2 * 16384;                // 256 KB
    int*    row_ptr = (int*)(wf_lo + LAYERS * 2 * 16384);              // 100001
    int*    cursor  = row_ptr + (N_NODES + 1);
    // zero-init region (single memset): deg, bsum, bpre, sums, cnt
    int*    deg     = cursor + N_NODES;
    int*    bsum    = deg + N_NODES;
    int*    bpre    = bsum + 512;
    float*  sums    = (float*)(bpre + 512);
    float*  cnt     = sums + (size_t)N_GRAPHS * HID;
    const size_t zbytes = (N_NODES + 512 + 512) * sizeof(int) +
                          ((size_t)N_GRAPHS * HID + N_GRAPHS) * sizeof(float);

    hipMemsetAsync(deg, 0, zbytes, stream);

    k_prep<<<NB_PROJ + NB_WCONV, 256, 0, stream>>>(x, inW, inb, h, hb0,
                                                   w1, w2, wf_hi, wf_lo);

    // CSR build (once per launch, reused across 4 layers)
    k_hist<<<NB_EDGE4, 256, 0, stream>>>(ei, deg);
    k_scan1<<<NB_SCAN, 256, 0, stream>>>(deg, bsum);
    k_scan2<<<1, 512, 0, stream>>>(bsum, bpre);
    k_scan3<<<NB_SCAN, 256, 0, stream>>>(deg, bpre, row_ptr, cursor);
    k_scatter<<<NB_EDGE4, 256, 0, stream>>>(ei, ea, cursor, edata);

    unsigned short* hbin = hb0;
    unsigned short* hbout = hb1;
    for (int l = 0; l < LAYERS; ++l) {
        k_node_update<<<N_NODES / 16, 256, 0, stream>>>(
            edata, row_ptr, edgeW + l * 3 * HID, edgeb + l * HID,
            h, hbin, hbout,
            wf_hi + (l * 2 + 0) * 16384, wf_lo + (l * 2 + 0) * 16384,
            wf_hi + (l * 2 + 1) * 16384, wf_lo + (l * 2 + 1) * 16384,
            b1 + l * HID, b2 + l * HID, gamma + l * HID, beta + l * HID);
        unsigned short* tmp = hbin; hbin = hbout; hbout = tmp;
    }
    // final h is in-place in `h` (fp32)

    k_pool<<<(N_NODES + 63) / 64, 128, 0, stream>>>(h, batch, sums, cnt);
    k_head<<<N_GRAPHS, 128, 0, stream>>>(sums, cnt, fcW1, fcb1, fcW2, fcb2,
                                         fcW3, fcb3, out);
}

// Round 16
// 730.012 us; speedup vs baseline: 1.0214x; 1.0214x over previous
//
#include <hip/hip_runtime.h>

#define N_NODES 100000
#define N_EDGES 1600000
#define N_GRAPHS 1024
#define HID 128
#define LAYERS 4
#define LN_EPS 1e-5f
#define NB_SCAN 391  // ceil(100000/256)
#define GTS 136      // ushort row stride for bf16 LDS planes (16B-aligned)
#define NB_PROJ 50000
#define NB_WCONV 512
#define NB_EDGE4 1563  // ceil(N_EDGES/4/256)

typedef __attribute__((ext_vector_type(8))) short bf16x8;
typedef __attribute__((ext_vector_type(4))) float f32x4;

__device__ __forceinline__ unsigned short f2bf(float x) {
    unsigned v = __float_as_uint(x);
    return (unsigned short)((v + 0x7fffu + ((v >> 16) & 1u)) >> 16);
}
__device__ __forceinline__ float bfval(unsigned short u) {
    return __uint_as_float((unsigned)u << 16);
}

// ------- prep: input projection + MFMA weight pre-swizzle ------------
__global__ __launch_bounds__(256) void k_prep(
    const float* __restrict__ x, const float* __restrict__ inW,
    const float* __restrict__ inb, float* __restrict__ h,
    unsigned short* __restrict__ hb,
    const float* __restrict__ w1, const float* __restrict__ w2,
    unsigned short* __restrict__ wf_hi, unsigned short* __restrict__ wf_lo) {
    if (blockIdx.x < NB_PROJ) {
        int idx = blockIdx.x * 256 + threadIdx.x;  // N_NODES*HID exact
        int n = idx >> 7, c = idx & 127;
        const float* xr = x + n * 7;
        float s = inb[c];
#pragma unroll
        for (int k = 0; k < 7; ++k) s += xr[k] * inW[k * HID + c];
        h[idx] = s;
        hb[idx] = f2bf(s);
    } else {
        int idx = (blockIdx.x - NB_PROJ) * 256 + threadIdx.x;  // LAYERS*2*16384
        int wid = idx >> 14;
        int layer = wid >> 1, which = wid & 1;
        int within = idx & 16383;
        int nt = within >> 11;
        int ks = (within >> 9) & 3;
        int ln = (within >> 3) & 63;
        int j = within & 7;
        const float* W = (which ? w2 : w1) + layer * HID * HID;
        int k = ks * 32 + (ln >> 4) * 8 + j;
        int n = nt * 16 + (ln & 15);
        float v = W[k * HID + n];
        unsigned short hi = f2bf(v);
        wf_hi[idx] = hi;
        wf_lo[idx] = f2bf(v - bfval(hi));
    }
}

// ---------------- CSR build: histogram of dst, 4 edges/thread --------
__global__ __launch_bounds__(256) void k_hist(
    const int* __restrict__ ei, int* __restrict__ deg) {
    const int e0 = (blockIdx.x * 256 + threadIdx.x) * 4;
    if (e0 + 4 <= N_EDGES) {
        const int4 d = *(const int4*)(ei + N_EDGES + e0);
        atomicAdd(&deg[d.x], 1);
        atomicAdd(&deg[d.y], 1);
        atomicAdd(&deg[d.z], 1);
        atomicAdd(&deg[d.w], 1);
    }
}

// ---------------- CSR build: parallel 3-stage scan -------------------
__global__ __launch_bounds__(256) void k_scan1(
    const int* __restrict__ deg, int* __restrict__ bsum) {
    const int i = blockIdx.x * 256 + threadIdx.x;
    int v = (i < N_NODES) ? deg[i] : 0;
#pragma unroll
    for (int off = 1; off < 64; off <<= 1) v += __shfl_xor(v, off);
    __shared__ int wsum[4];
    if ((threadIdx.x & 63) == 0) wsum[threadIdx.x >> 6] = v;
    __syncthreads();
    if (threadIdx.x == 0) bsum[blockIdx.x] = wsum[0] + wsum[1] + wsum[2] + wsum[3];
}

__global__ __launch_bounds__(512) void k_scan2(
    const int* __restrict__ bsum, int* __restrict__ bpre) {
    __shared__ int tmp[512];
    const int t = threadIdx.x;
    int v = (t < NB_SCAN) ? bsum[t] : 0;
    tmp[t] = v;
    __syncthreads();
    for (int off = 1; off < 512; off <<= 1) {
        int u = (t >= off) ? tmp[t - off] : 0;
        __syncthreads();
        tmp[t] += u;
        __syncthreads();
    }
    if (t < NB_SCAN) bpre[t] = tmp[t] - v;  // exclusive
}

__global__ __launch_bounds__(256) void k_scan3(
    const int* __restrict__ deg, const int* __restrict__ bpre,
    int* __restrict__ row_ptr, int* __restrict__ cursor) {
    __shared__ int tmp[256];
    const int t = threadIdx.x;
    const int i = blockIdx.x * 256 + t;
    int d = (i < N_NODES) ? deg[i] : 0;
    tmp[t] = d;
    __syncthreads();
    for (int off = 1; off < 256; off <<= 1) {
        int u = (t >= off) ? tmp[t - off] : 0;
        __syncthreads();
        tmp[t] += u;
        __syncthreads();
    }
    if (i < N_NODES) {
        const int ex = bpre[blockIdx.x] + tmp[t] - d;
        row_ptr[i] = ex;
        cursor[i] = ex;
        if (i == N_NODES - 1) row_ptr[N_NODES] = N_EDGES;
    }
}

// ------- CSR build: SoA scatter (R15 lesson: 16B random stores to a
// 25.6MB AoS array expand to full-line HBM writes, WRITE=101MB. Split
// streams: esrc 6.4MB (16 stores/line, L2-resident) + eattr 19.2MB.)
__global__ __launch_bounds__(256) void k_scatter(
    const int* __restrict__ ei, const float* __restrict__ ea,
    int* __restrict__ cursor, int* __restrict__ esrc,
    float* __restrict__ eattr) {
    int e = blockIdx.x * 256 + threadIdx.x;  // N_EDGES exact
    const int src = ei[e];
    const int dst = ei[N_EDGES + e];
    const float a0 = ea[e * 3 + 0];
    const float a1 = ea[e * 3 + 1];
    const float a2 = ea[e * 3 + 2];
    const int pos = atomicAdd(&cursor[dst], 1);
    esrc[pos] = src;
    eattr[(size_t)pos * 3 + 0] = a0;
    eattr[(size_t)pos * 3 + 1] = a1;
    eattr[(size_t)pos * 3 + 2] = a2;
}

// -- phase-1 edge macros (macros only: outlined helpers spill, R4/R5) --
// Edge tile in registers (cS/cA* = per-lane edge); attrs/src via
// v_readlane. Row selection: RUNNING accumulator + scalar boundary flush.
#define FLUSHSTEP {                                                            \
    if (rcur == 0)      { a0x = ax; a0y = ay; rnext = rp2; }                   \
    else if (rcur == 1) { a1x = ax; a1y = ay; rnext = rp3; }                   \
    else                { a2x = ax; a2y = ay; rnext = 0x7fffffff; }            \
    ax = 0.f; ay = 0.f; ++rcur; }

#define EL(JJ)                                                                 \
    const int s##JJ = __builtin_amdgcn_readlane(cS, j + JJ);                   \
    const unsigned gq##JJ = *(const unsigned*)(hbin + (long)s##JJ * HID + c2);

#define EC(JJ) {                                                               \
    const int gi = t + j + (JJ);                                               \
    while (gi >= rnext) FLUSHSTEP                                              \
    const float ax_ = __uint_as_float(__builtin_amdgcn_readlane(__float_as_int(cA0), j + JJ)); \
    const float ay_ = __uint_as_float(__builtin_amdgcn_readlane(__float_as_int(cA1), j + JJ)); \
    const float az_ = __uint_as_float(__builtin_amdgcn_readlane(__float_as_int(cA2), j + JJ)); \
    const float gx = __uint_as_float(gq##JJ << 16) + ebv.x;                    \
    const float gy = __uint_as_float(gq##JJ & 0xffff0000u) + ebv.y;            \
    const float mx = fmaxf(fmaf(az_, ew2.x, fmaf(ay_, ew1.x, fmaf(ax_, ew0.x, gx))), 0.f); \
    const float my = fmaxf(fmaf(az_, ew2.y, fmaf(ay_, ew1.y, fmaf(ax_, ew0.y, gy))), 0.f); \
    ax += mx; ay += my; }

#define ROW_OUT(R, AX, AY) {                                                   \
    const float2 hv = *(const float2*)(h + (long)(nb + (R)) * HID + c2);       \
    const float gx = hv.x + (AX), gy = hv.y + (AY);                            \
    const unsigned short hx = f2bf(gx), hy = f2bf(gy);                         \
    const unsigned short lx = f2bf(gx - bfval(hx)), ly = f2bf(gy - bfval(hy)); \
    *(unsigned*)&gt_hi[(r0 + (R)) * GTS + c2] = (unsigned)hx | ((unsigned)hy << 16); \
    *(unsigned*)&gt_lo[(r0 + (R)) * GTS + c2] = (unsigned)lx | ((unsigned)ly << 16); }

#define T1_OUT(CC, NT) {                                                       \
    const float4 bv = *(const float4*)(b1 + (NT) * 16 + q4);                   \
    const float v0 = fmaxf(CC[0] + bv.x, 0.f);                                 \
    const float v1 = fmaxf(CC[1] + bv.y, 0.f);                                 \
    const float v2 = fmaxf(CC[2] + bv.z, 0.f);                                 \
    const float v3 = fmaxf(CC[3] + bv.w, 0.f);                                 \
    const unsigned short h0_ = f2bf(v0), h1_ = f2bf(v1), h2_ = f2bf(v2), h3_ = f2bf(v3); \
    const unsigned short l0_ = f2bf(v0 - bfval(h0_)), l1_ = f2bf(v1 - bfval(h1_)); \
    const unsigned short l2_ = f2bf(v2 - bfval(h2_)), l3_ = f2bf(v3 - bfval(h3_)); \
    *(uint2*)&t1_hi[ln15 * GTS + (NT) * 16 + q4] =                             \
        make_uint2((unsigned)h0_ | ((unsigned)h1_ << 16), (unsigned)h2_ | ((unsigned)h3_ << 16)); \
    *(uint2*)&t1_lo[ln15 * GTS + (NT) * 16 + q4] =                             \
        make_uint2((unsigned)l0_ | ((unsigned)l1_ << 16), (unsigned)l2_ | ((unsigned)l3_ << 16)); }

// ------- fused gather-aggregate + MFMA MLP + residual + layernorm ----
__global__ __launch_bounds__(256, 8) void k_node_update(
    const int* __restrict__ esrc, const float* __restrict__ eattr,
    const int* __restrict__ row_ptr,
    const float* __restrict__ eW, const float* __restrict__ eb,
    float* __restrict__ h, const unsigned short* __restrict__ hbin,
    unsigned short* __restrict__ hbout,
    const unsigned short* __restrict__ w1f_hi, const unsigned short* __restrict__ w1f_lo,
    const unsigned short* __restrict__ w2f_hi, const unsigned short* __restrict__ w2f_lo,
    const float* __restrict__ b1, const float* __restrict__ b2,
    const float* __restrict__ gamma, const float* __restrict__ beta) {
    __shared__ __align__(16) unsigned char smem[17408];
    float* stats = (float*)smem;                              // [4][32] f32, phase 3 (aliases gt_hi)
    unsigned short* gt_hi = (unsigned short*)(smem + 0);      // [16][GTS]
    unsigned short* gt_lo = (unsigned short*)(smem + 4352);
    unsigned short* t1_hi = (unsigned short*)(smem + 8704);
    unsigned short* t1_lo = (unsigned short*)(smem + 13056);

    const int wave = threadIdx.x >> 6;
    const int lane = threadIdx.x & 63;
    const int n0 = blockIdx.x * 16;
    const int r0 = wave * 4;
    const int c2 = lane * 2;

    // ---- phase 1: gather-aggregate, full wave per edge, zero LDS ----
    {
        const float2 ew0 = *(const float2*)(eW + 0 * HID + c2);
        const float2 ew1 = *(const float2*)(eW + 1 * HID + c2);
        const float2 ew2 = *(const float2*)(eW + 2 * HID + c2);
        const float2 ebv = *(const float2*)(eb + c2);
        const int nb = n0 + r0;
        const int rp0 = __builtin_amdgcn_readfirstlane(row_ptr[nb + 0]);
        const int rp1 = __builtin_amdgcn_readfirstlane(row_ptr[nb + 1]);
        const int rp2 = __builtin_amdgcn_readfirstlane(row_ptr[nb + 2]);
        const int rp3 = __builtin_amdgcn_readfirstlane(row_ptr[nb + 3]);
        const int rp4 = __builtin_amdgcn_readfirstlane(row_ptr[nb + 4]);

        float a0x = 0.f, a0y = 0.f, a1x = 0.f, a1y = 0.f;
        float a2x = 0.f, a2y = 0.f, a3x = 0.f, a3y = 0.f;
        float ax = 0.f, ay = 0.f;   // running accumulator (current row)
        int rcur = 0;               // current row index (scalar)
        int rnext = rp1;            // next row boundary

        int cS, nS;
        float cA0, cA1, cA2, nA0, nA1, nA2;
        if (rp0 + lane < rp4) {
            cS = esrc[rp0 + lane];
            cA0 = eattr[(size_t)(rp0 + lane) * 3 + 0];
            cA1 = eattr[(size_t)(rp0 + lane) * 3 + 1];
            cA2 = eattr[(size_t)(rp0 + lane) * 3 + 2];
        }
        for (int t = rp0; t < rp4; t += 64) {
            const int cnt = (rp4 - t < 64) ? (rp4 - t) : 64;
            if (t + 64 + lane < rp4) {  // prefetch next tile
                nS = esrc[t + 64 + lane];
                nA0 = eattr[(size_t)(t + 64 + lane) * 3 + 0];
                nA1 = eattr[(size_t)(t + 64 + lane) * 3 + 1];
                nA2 = eattr[(size_t)(t + 64 + lane) * 3 + 2];
            }
            int j = 0;
            for (; j + 16 <= cnt; j += 16) {
                EL(0) EL(1) EL(2) EL(3) EL(4) EL(5) EL(6) EL(7)
                EL(8) EL(9) EL(10) EL(11) EL(12) EL(13) EL(14) EL(15)
                EC(0) EC(1) EC(2) EC(3) EC(4) EC(5) EC(6) EC(7)
                EC(8) EC(9) EC(10) EC(11) EC(12) EC(13) EC(14) EC(15)
            }
            for (; j + 4 <= cnt; j += 4) {
                EL(0) EL(1) EL(2) EL(3)
                EC(0) EC(1) EC(2) EC(3)
            }
            for (; j < cnt; ++j) {
                EL(0)
                EC(0)
            }
            cS = nS; cA0 = nA0; cA1 = nA1; cA2 = nA2;
        }
        // tail: running acc belongs to row rcur; rows after it stay zero
        if (rcur == 0)      { a0x = ax; a0y = ay; }
        else if (rcur == 1) { a1x = ax; a1y = ay; }
        else if (rcur == 2) { a2x = ax; a2y = ay; }
        else                { a3x = ax; a3y = ay; }
        ROW_OUT(0, a0x, a0y)
        ROW_OUT(1, a1x, a1y)
        ROW_OUT(2, a2x, a2y)
        ROW_OUT(3, a3x, a3y)
    }
    __syncthreads();

    const int ln15 = lane & 15;
    const int q8 = (lane >> 4) * 8;
    const int q4 = (lane >> 4) * 4;
    const int nt0 = wave * 2, nt1 = nt0 + 1;

    // ---- phase 2: t1 = relu(gt @ w1 + b1) via MFMA (D[hid][node]) ----
    {
        f32x4 c0 = {0.f, 0.f, 0.f, 0.f};
        f32x4 c1 = {0.f, 0.f, 0.f, 0.f};
#pragma unroll
        for (int ks = 0; ks < 4; ++ks) {
            const bf16x8 bh = *(const bf16x8*)&gt_hi[ln15 * GTS + ks * 32 + q8];
            const bf16x8 bl = *(const bf16x8*)&gt_lo[ln15 * GTS + ks * 32 + q8];
            const bf16x8 a0h = *(const bf16x8*)(w1f_hi + (((nt0 * 4 + ks) * 64 + lane) << 3));
            const bf16x8 a0l = *(const bf16x8*)(w1f_lo + (((nt0 * 4 + ks) * 64 + lane) << 3));
            const bf16x8 a1h = *(const bf16x8*)(w1f_hi + (((nt1 * 4 + ks) * 64 + lane) << 3));
            const bf16x8 a1l = *(const bf16x8*)(w1f_lo + (((nt1 * 4 + ks) * 64 + lane) << 3));
            c0 = __builtin_amdgcn_mfma_f32_16x16x32_bf16(a0h, bh, c0, 0, 0, 0);
            c0 = __builtin_amdgcn_mfma_f32_16x16x32_bf16(a0h, bl, c0, 0, 0, 0);
            c0 = __builtin_amdgcn_mfma_f32_16x16x32_bf16(a0l, bh, c0, 0, 0, 0);
            c1 = __builtin_amdgcn_mfma_f32_16x16x32_bf16(a1h, bh, c1, 0, 0, 0);
            c1 = __builtin_amdgcn_mfma_f32_16x16x32_bf16(a1h, bl, c1, 0, 0, 0);
            c1 = __builtin_amdgcn_mfma_f32_16x16x32_bf16(a1l, bh, c1, 0, 0, 0);
        }
        T1_OUT(c0, nt0)
        T1_OUT(c1, nt1)
    }
    __syncthreads();

    // ---- phase 3: u = h + relu(t1 @ w2 + b2) in regs; fused LN ----
    {
        f32x4 c0 = {0.f, 0.f, 0.f, 0.f};
        f32x4 c1 = {0.f, 0.f, 0.f, 0.f};
#pragma unroll
        for (int ks = 0; ks < 4; ++ks) {
            const bf16x8 bh = *(const bf16x8*)&t1_hi[ln15 * GTS + ks * 32 + q8];
            const bf16x8 bl = *(const bf16x8*)&t1_lo[ln15 * GTS + ks * 32 + q8];
            const bf16x8 a0h = *(const bf16x8*)(w2f_hi + (((nt0 * 4 + ks) * 64 + lane) << 3));
            const bf16x8 a0l = *(const bf16x8*)(w2f_lo + (((nt0 * 4 + ks) * 64 + lane) << 3));
            const bf16x8 a1h = *(const bf16x8*)(w2f_hi + (((nt1 * 4 + ks) * 64 + lane) << 3));
            const bf16x8 a1l = *(const bf16x8*)(w2f_lo + (((nt1 * 4 + ks) * 64 + lane) << 3));
            c0 = __builtin_amdgcn_mfma_f32_16x16x32_bf16(a0h, bh, c0, 0, 0, 0);
            c0 = __builtin_amdgcn_mfma_f32_16x16x32_bf16(a0h, bl, c0, 0, 0, 0);
            c0 = __builtin_amdgcn_mfma_f32_16x16x32_bf16(a0l, bh, c0, 0, 0, 0);
            c1 = __builtin_amdgcn_mfma_f32_16x16x32_bf16(a1h, bh, c1, 0, 0, 0);
            c1 = __builtin_amdgcn_mfma_f32_16x16x32_bf16(a1h, bl, c1, 0, 0, 0);
            c1 = __builtin_amdgcn_mfma_f32_16x16x32_bf16(a1l, bh, c1, 0, 0, 0);
        }
        const int row = n0 + ln15;
        const float4 b20 = *(const float4*)(b2 + nt0 * 16 + q4);
        const float4 b21 = *(const float4*)(b2 + nt1 * 16 + q4);
        const float4 hv0 = *(const float4*)(h + (long)row * HID + nt0 * 16 + q4);
        const float4 hv1 = *(const float4*)(h + (long)row * HID + nt1 * 16 + q4);
        float4 u0, u1;
        u0.x = hv0.x + fmaxf(c0[0] + b20.x, 0.f);
        u0.y = hv0.y + fmaxf(c0[1] + b20.y, 0.f);
        u0.z = hv0.z + fmaxf(c0[2] + b20.z, 0.f);
        u0.w = hv0.w + fmaxf(c0[3] + b20.w, 0.f);
        u1.x = hv1.x + fmaxf(c1[0] + b21.x, 0.f);
        u1.y = hv1.y + fmaxf(c1[1] + b21.y, 0.f);
        u1.z = hv1.z + fmaxf(c1[2] + b21.z, 0.f);
        u1.w = hv1.w + fmaxf(c1[3] + b21.w, 0.f);
        float s = u0.x + u0.y + u0.z + u0.w + u1.x + u1.y + u1.z + u1.w;
        float s2 = u0.x * u0.x + u0.y * u0.y + u0.z * u0.z + u0.w * u0.w +
                   u1.x * u1.x + u1.y * u1.y + u1.z * u1.z + u1.w * u1.w;
        s += __shfl_xor(s, 16); s2 += __shfl_xor(s2, 16);
        s += __shfl_xor(s, 32); s2 += __shfl_xor(s2, 32);
        if (lane < 16) {
            stats[wave * 32 + lane * 2 + 0] = s;
            stats[wave * 32 + lane * 2 + 1] = s2;
        }
        __syncthreads();
        const float S  = stats[0 * 32 + ln15 * 2] + stats[1 * 32 + ln15 * 2] +
                         stats[2 * 32 + ln15 * 2] + stats[3 * 32 + ln15 * 2];
        const float S2 = stats[0 * 32 + ln15 * 2 + 1] + stats[1 * 32 + ln15 * 2 + 1] +
                         stats[2 * 32 + ln15 * 2 + 1] + stats[3 * 32 + ln15 * 2 + 1];
        const float mu = S * (1.f / HID);
        const float var = S2 * (1.f / HID) - mu * mu;
        const float inv = rsqrtf(var + LN_EPS);
        const float4 gm0 = *(const float4*)(gamma + nt0 * 16 + q4);
        const float4 gm1 = *(const float4*)(gamma + nt1 * 16 + q4);
        const float4 bt0 = *(const float4*)(beta + nt0 * 16 + q4);
        const float4 bt1 = *(const float4*)(beta + nt1 * 16 + q4);
        float4 o0, o1;
        o0.x = (u0.x - mu) * inv * gm0.x + bt0.x;
        o0.y = (u0.y - mu) * inv * gm0.y + bt0.y;
        o0.z = (u0.z - mu) * inv * gm0.z + bt0.z;
        o0.w = (u0.w - mu) * inv * gm0.w + bt0.w;
        o1.x = (u1.x - mu) * inv * gm1.x + bt1.x;
        o1.y = (u1.y - mu) * inv * gm1.y + bt1.y;
        o1.z = (u1.z - mu) * inv * gm1.z + bt1.z;
        o1.w = (u1.w - mu) * inv * gm1.w + bt1.w;
        *(float4*)(h + (long)row * HID + nt0 * 16 + q4) = o0;
        *(float4*)(h + (long)row * HID + nt1 * 16 + q4) = o1;
        *(uint2*)(hbout + (long)row * HID + nt0 * 16 + q4) =
            make_uint2((unsigned)f2bf(o0.x) | ((unsigned)f2bf(o0.y) << 16),
                       (unsigned)f2bf(o0.z) | ((unsigned)f2bf(o0.w) << 16));
        *(uint2*)(hbout + (long)row * HID + nt1 * 16 + q4) =
            make_uint2((unsigned)f2bf(o1.x) | ((unsigned)f2bf(o1.y) << 16),
                       (unsigned)f2bf(o1.z) | ((unsigned)f2bf(o1.w) << 16));
    }
}

// -------- global mean pool: segmented reduction (batch is sorted) ----
__global__ __launch_bounds__(128) void k_pool(
    const float* __restrict__ h, const int* __restrict__ batch,
    float* __restrict__ sums, float* __restrict__ cnt) {
    const int c = threadIdx.x;
    const int n0 = blockIdx.x * 64;
    if (n0 >= N_NODES) return;
    const int nend = min(n0 + 64, N_NODES);
    int cur = batch[n0];
    float acc = 0.f;
    int runlen = 0;
    for (int n = n0; n < nend; ++n) {
        const int b = batch[n];
        if (b != cur) {
            atomicAdd(&sums[(long)cur * HID + c], acc);
            if (c == 0) atomicAdd(&cnt[cur], (float)runlen);
            acc = 0.f;
            runlen = 0;
            cur = b;
        }
        acc += h[(long)n * HID + c];
        ++runlen;
    }
    atomicAdd(&sums[(long)cur * HID + c], acc);
    if (c == 0) atomicAdd(&cnt[cur], (float)runlen);
}

// ---------------- head: 1 block per graph ----------------------------
__global__ __launch_bounds__(128) void k_head(
    const float* __restrict__ sums, const float* __restrict__ cnt,
    const float* __restrict__ fcW1, const float* __restrict__ fcb1,
    const float* __restrict__ fcW2, const float* __restrict__ fcb2,
    const float* __restrict__ fcW3, const float* __restrict__ fcb3,
    float* __restrict__ out) {
    __shared__ float p[HID];
    __shared__ float o1[HID];
    __shared__ float o2[64];
    const int g = blockIdx.x, t = threadIdx.x;
    const float c = fmaxf(cnt[g], 1.0f);
    p[t] = sums[g * HID + t] / c;
    __syncthreads();
    float s = fcb1[t];
    for (int k = 0; k < HID; ++k) s += p[k] * fcW1[k * HID + t];
    o1[t] = fmaxf(s, 0.f);
    __syncthreads();
    if (t < 64) {
        float s2 = fcb2[t];
        for (int k = 0; k < HID; ++k) s2 += o1[k] * fcW2[k * 64 + t];
        o2[t] = fmaxf(s2, 0.f);
    }
    __syncthreads();
    if (t < 64) {
        float v = o2[t] * fcW3[t];
#pragma unroll
        for (int off = 32; off > 0; off >>= 1) v += __shfl_down(v, off);
        if (t == 0) out[g] = v + fcb3[0];
    }
}

extern "C" void kernel_launch(void* const* d_in, const int* in_sizes, int n_in,
                              void* d_out, int out_size, void* d_ws, size_t ws_size,
                              hipStream_t stream) {
    const float* x    = (const float*)d_in[0];
    const int*   ei   = (const int*)d_in[1];
    const float* ea   = (const float*)d_in[2];
    const int*   batch= (const int*)d_in[3];
    const float* inW  = (const float*)d_in[4];
    const float* inb  = (const float*)d_in[5];
    const float* edgeW= (const float*)d_in[6];
    const float* edgeb= (const float*)d_in[7];
    const float* w1   = (const float*)d_in[8];
    const float* b1   = (const float*)d_in[9];
    const float* w2   = (const float*)d_in[10];
    const float* b2   = (const float*)d_in[11];
    const float* gamma= (const float*)d_in[12];
    const float* beta = (const float*)d_in[13];
    const float* fcW1 = (const float*)d_in[14];
    const float* fcb1 = (const float*)d_in[15];
    const float* fcW2 = (const float*)d_in[16];
    const float* fcb2 = (const float*)d_in[17];
    const float* fcW3 = (const float*)d_in[18];
    const float* fcb3 = (const float*)d_in[19];
    float* out = (float*)d_out;

    // workspace layout (16B-aligned blocks first): ~129 MB
    float* eattr = (float*)d_ws;                                       // 19.2 MB
    float* h     = eattr + (size_t)N_EDGES * 3;                        // 51.2 MB
    unsigned short* hb0 = (unsigned short*)(h + (size_t)N_NODES * HID);// 25.6 MB
    unsigned short* hb1 = hb0 + (size_t)N_NODES * HID;                 // 25.6 MB
    unsigned short* wf_hi = hb1 + (size_t)N_NODES * HID;               // 256 KB
    unsigned short* wf_lo = wf_hi + LAYERS * 2 * 16384;                // 256 KB
    int*    esrc    = (int*)(wf_lo + LAYERS * 2 * 16384);              // 6.4 MB
    int*    row_ptr = esrc + N_EDGES;                                  // 100001
    int*    cursor  = row_ptr + (N_NODES + 1);
    // zero-init region (single memset): deg, bsum, bpre, sums, cnt
    int*    deg     = cursor + N_NODES;
    int*    bsum    = deg + N_NODES;
    int*    bpre    = bsum + 512;
    float*  sums    = (float*)(bpre + 512);
    float*  cnt     = sums + (size_t)N_GRAPHS * HID;
    const size_t zbytes = (N_NODES + 512 + 512) * sizeof(int) +
                          ((size_t)N_GRAPHS * HID + N_GRAPHS) * sizeof(float);

    hipMemsetAsync(deg, 0, zbytes, stream);

    k_prep<<<NB_PROJ + NB_WCONV, 256, 0, stream>>>(x, inW, inb, h, hb0,
                                                   w1, w2, wf_hi, wf_lo);

    // CSR build (once per launch, reused across 4 layers)
    k_hist<<<NB_EDGE4, 256, 0, stream>>>(ei, deg);
    k_scan1<<<NB_SCAN, 256, 0, stream>>>(deg, bsum);
    k_scan2<<<1, 512, 0, stream>>>(bsum, bpre);
    k_scan3<<<NB_SCAN, 256, 0, stream>>>(deg, bpre, row_ptr, cursor);
    k_scatter<<<N_EDGES / 256, 256, 0, stream>>>(ei, ea, cursor, esrc, eattr);

    unsigned short* hbin = hb0;
    unsigned short* hbout = hb1;
    for (int l = 0; l < LAYERS; ++l) {
        k_node_update<<<N_NODES / 16, 256, 0, stream>>>(
            esrc, eattr, row_ptr, edgeW + l * 3 * HID, edgeb + l * HID,
            h, hbin, hbout,
            wf_hi + (l * 2 + 0) * 16384, wf_lo + (l * 2 + 0) * 16384,
            wf_hi + (l * 2 + 1) * 16384, wf_lo + (l * 2 + 1) * 16384,
            b1 + l * HID, b2 + l * HID, gamma + l * HID, beta + l * HID);
        unsigned short* tmp = hbin; hbin = hbout; hbout = tmp;
    }
    // final h is in-place in `h` (fp32)

    k_pool<<<(N_NODES + 63) / 64, 128, 0, stream>>>(h, batch, sums, cnt);
    k_head<<<N_GRAPHS, 128, 0, stream>>>(sums, cnt, fcW1, fcb1, fcW2, fcb2,
                                         fcW3, fcb3, out);
}